// Round 1
// baseline (631.757 us; speedup 1.0000x reference)
//
#include <hip/hip_runtime.h>
#include <math.h>

#define NN 50000
#define EE 600000
#define GG 250
#define HH 128

// ---------- CSR build ----------
__global__ void hist_k(const int* __restrict__ dst, int* __restrict__ deg) {
  int e = blockIdx.x * 256 + threadIdx.x;
  if (e < EE) atomicAdd(&deg[dst[e]], 1);
}

__global__ void scan_k(const int* __restrict__ deg, int* __restrict__ rowptr,
                       int* __restrict__ wp) {
  __shared__ int sums[16];
  __shared__ int s_carry;
  int tid = threadIdx.x;
  if (tid == 0) s_carry = 0;
  __syncthreads();
  for (int base = 0; base < NN; base += 1024) {
    int i = base + tid;
    int v = (i < NN) ? deg[i] : 0;
    int lane = tid & 63, wid = tid >> 6;
    int x = v;
    #pragma unroll
    for (int d = 1; d < 64; d <<= 1) { int y = __shfl_up(x, d); if (lane >= d) x += y; }
    if (lane == 63) sums[wid] = x;
    __syncthreads();
    if (wid == 0) {
      int s = (lane < 16) ? sums[lane] : 0;
      #pragma unroll
      for (int d = 1; d < 16; d <<= 1) { int y = __shfl_up(s, d); if (lane >= d) s += y; }
      if (lane < 16) sums[lane] = s;
    }
    __syncthreads();
    int off = s_carry + (wid ? sums[wid - 1] : 0);
    int excl = off + x - v;
    if (i < NN) { rowptr[i] = excl; wp[i] = excl; }
    __syncthreads();
    if (tid == 0) s_carry += sums[15];
    __syncthreads();
  }
  if (tid == 0) rowptr[NN] = s_carry;
}

__global__ void scatter_k(const int* __restrict__ src, const int* __restrict__ dst,
                          int* __restrict__ wp, int* __restrict__ eidx) {
  int e = blockIdx.x * 256 + threadIdx.x;
  if (e < EE) {
    int p = atomicAdd(&wp[dst[e]], 1);
    eidx[p] = src[e];
  }
}

__global__ void root_k(const int* __restrict__ batch, int* __restrict__ root) {
  int n = blockIdx.x * 256 + threadIdx.x;
  if (n < NN) atomicMin(&root[batch[n]], n);
}

// ---------- mean aggregation (gather over CSR), one wave per node ----------
__global__ void agg_k(const float* __restrict__ hin, const int* __restrict__ rowptr,
                      const int* __restrict__ eidx, float* __restrict__ agg) {
  int wave = threadIdx.x >> 6, lane = threadIdx.x & 63;
  int n = blockIdx.x * 4 + wave;
  int start = rowptr[n], end = rowptr[n + 1];
  float2 acc; acc.x = 0.f; acc.y = 0.f;
  int basei = start;
  while (basei < end) {
    int m = end - basei; if (m > 64) m = 64;
    int sl = (lane < m) ? eidx[basei + lane] : 0;
    for (int t = 0; t < m; ++t) {
      int s = __shfl(sl, t);
      float2 v = *(const float2*)&hin[s * HH + lane * 2];
      acc.x += v.x; acc.y += v.y;
    }
    basei += m;
  }
  int c = end - start;
  float inv = 1.f / (float)(c > 0 ? c : 1);
  float2 o; o.x = acc.x * inv; o.y = acc.y * inv;
  *(float2*)&agg[n * HH + lane * 2] = o;
}

// ---------- fused (agg@Wl + bl + h@Wr) -> L2 normalize -> relu ----------
#define FMA4(vv, a4, w0, w1, w2, w3)                                   \
  vv.x += a4.x*w0.x + a4.y*w1.x + a4.z*w2.x + a4.w*w3.x;               \
  vv.y += a4.x*w0.y + a4.y*w1.y + a4.z*w2.y + a4.w*w3.y;               \
  vv.z += a4.x*w0.z + a4.y*w1.z + a4.z*w2.z + a4.w*w3.z;               \
  vv.w += a4.x*w0.w + a4.y*w1.w + a4.z*w2.w + a4.w*w3.w;

__global__ __launch_bounds__(256) void sage_k(
    const float* __restrict__ agg, const float* __restrict__ hin,
    const float* __restrict__ Wl, const float* __restrict__ bl,
    const float* __restrict__ Wr, float* __restrict__ hout) {
  __shared__ float sA[64 * 128];
  __shared__ float sH[64 * 128];
  int tid = threadIdx.x;
  int row0 = blockIdx.x * 64;
  // stage 64x128 tiles of agg and hin
  #pragma unroll
  for (int i = 0; i < 8; ++i) {
    int off = (i * 256 + tid) * 4;     // float index within tile
    int row = row0 + (off >> 7);
    float4 a = {0.f, 0.f, 0.f, 0.f}, h = {0.f, 0.f, 0.f, 0.f};
    if (row < NN) {
      a = *(const float4*)&agg[row0 * HH + off];
      h = *(const float4*)&hin[row0 * HH + off];
    }
    *(float4*)&sA[off] = a;
    *(float4*)&sH[off] = h;
  }
  __syncthreads();

  int jg = tid & 31, rg = tid >> 5;     // 32 col-groups x 8 row-groups
  float4 b4 = *(const float4*)&bl[jg * 4];
  float4 v[8];
  #pragma unroll
  for (int r = 0; r < 8; ++r) v[r] = b4;
  const float* sAr = &sA[(rg * 8) * 128];
  const float* sHr = &sH[(rg * 8) * 128];

  for (int k = 0; k < 128; k += 4) {
    float4 wl0 = *(const float4*)&Wl[(k + 0) * 128 + jg * 4];
    float4 wl1 = *(const float4*)&Wl[(k + 1) * 128 + jg * 4];
    float4 wl2 = *(const float4*)&Wl[(k + 2) * 128 + jg * 4];
    float4 wl3 = *(const float4*)&Wl[(k + 3) * 128 + jg * 4];
    float4 wr0 = *(const float4*)&Wr[(k + 0) * 128 + jg * 4];
    float4 wr1 = *(const float4*)&Wr[(k + 1) * 128 + jg * 4];
    float4 wr2 = *(const float4*)&Wr[(k + 2) * 128 + jg * 4];
    float4 wr3 = *(const float4*)&Wr[(k + 3) * 128 + jg * 4];
    #pragma unroll
    for (int r = 0; r < 8; ++r) {
      float4 a4 = *(const float4*)&sAr[r * 128 + k];
      float4 h4 = *(const float4*)&sHr[r * 128 + k];
      FMA4(v[r], a4, wl0, wl1, wl2, wl3);
      FMA4(v[r], h4, wr0, wr1, wr2, wr3);
    }
  }

  // per-row L2 norm over 128 cols = reduce across 32 col-groups (same wave half)
  float s[8];
  #pragma unroll
  for (int r = 0; r < 8; ++r)
    s[r] = v[r].x * v[r].x + v[r].y * v[r].y + v[r].z * v[r].z + v[r].w * v[r].w;
  #pragma unroll
  for (int d = 1; d < 32; d <<= 1) {
    #pragma unroll
    for (int r = 0; r < 8; ++r) s[r] += __shfl_xor(s[r], d);
  }
  #pragma unroll
  for (int r = 0; r < 8; ++r) {
    float inv = 1.f / fmaxf(sqrtf(s[r]), 1e-12f);
    int row = row0 + rg * 8 + r;
    if (row < NN) {
      float4 o;
      o.x = fmaxf(v[r].x * inv, 0.f);
      o.y = fmaxf(v[r].y * inv, 0.f);
      o.z = fmaxf(v[r].z * inv, 0.f);
      o.w = fmaxf(v[r].w * inv, 0.f);
      *(float4*)&hout[row * HH + jg * 4] = o;
    }
  }
}

// ---------- global max pool per graph ----------
__global__ void pool_k(const float* __restrict__ h, const int* __restrict__ root,
                       float* __restrict__ hg) {
  int g = blockIdx.x, j = threadIdx.x;
  int start = root[g], end = (g == GG - 1) ? NN : root[g + 1];
  float m = -1e30f;
  for (int i = start; i < end; ++i) m = fmaxf(m, h[i * HH + j]);
  hg[g * HH + j] = m;
}

// ---------- news = relu(x[root] @ Wnews + b) ----------
__global__ void news_k(const float* __restrict__ x, const int* __restrict__ root,
                       const float* __restrict__ W, const float* __restrict__ b,
                       float* __restrict__ news) {
  __shared__ float xr[128];
  int g = blockIdx.x, j = threadIdx.x;
  int r = root[g];
  xr[j] = x[r * HH + j];
  __syncthreads();
  float acc = b[j];
  for (int k = 0; k < 128; ++k) acc += xr[k] * W[k * HH + j];
  news[g * HH + j] = fmaxf(acc, 0.f);
}

// ---------- hg2 = relu(hg@Wlin2+b2); out = sigmoid([hg2,news]@Wlin3+b3) ----------
__global__ void final_k(const float* __restrict__ hg, const float* __restrict__ news,
                        const float* __restrict__ W2, const float* __restrict__ b2,
                        const float* __restrict__ W3, const float* __restrict__ b3,
                        float* __restrict__ out) {
  __shared__ float hgr[128];
  __shared__ float red[2];
  int g = blockIdx.x, j = threadIdx.x;
  hgr[j] = hg[g * HH + j];
  __syncthreads();
  float acc = b2[j];
  for (int k = 0; k < 128; ++k) acc += hgr[k] * W2[k * HH + j];
  float v2 = fmaxf(acc, 0.f);
  float c = v2 * W3[j] + news[g * HH + j] * W3[HH + j];
  #pragma unroll
  for (int d = 1; d < 64; d <<= 1) c += __shfl_xor(c, d);
  if ((j & 63) == 0) red[j >> 6] = c;
  __syncthreads();
  if (j == 0) {
    float z = red[0] + red[1] + b3[0];
    out[g] = 1.f / (1.f + expf(-z));
  }
}

extern "C" void kernel_launch(void* const* d_in, const int* in_sizes, int n_in,
                              void* d_out, int out_size, void* d_ws, size_t ws_size,
                              hipStream_t stream) {
  const float* x     = (const float*)d_in[0];
  const int*   adj   = (const int*)d_in[1];
  const int*   batch = (const int*)d_in[2];
  const float *W1l = (const float*)d_in[3],  *b1l = (const float*)d_in[4],  *W1r = (const float*)d_in[5];
  const float *W2l = (const float*)d_in[6],  *b2l = (const float*)d_in[7],  *W2r = (const float*)d_in[8];
  const float *W3l = (const float*)d_in[9],  *b3l = (const float*)d_in[10], *W3r = (const float*)d_in[11];
  const float *Wnews = (const float*)d_in[12], *bnews = (const float*)d_in[13];
  const float *Wlin2 = (const float*)d_in[14], *blin2 = (const float*)d_in[15];
  const float *Wlin3 = (const float*)d_in[16], *blin3 = (const float*)d_in[17];
  float* out = (float*)d_out;

  const int* srcp = adj;       // adj[0]
  const int* dstp = adj + EE;  // adj[1]

  // workspace layout
  char* ws = (char*)d_ws;
  size_t off = 0;
  auto alloc = [&](size_t bytes) -> void* {
    void* p = ws + off;
    off = (off + bytes + 255) & ~(size_t)255;
    return p;
  };
  int*   deg    = (int*)alloc(sizeof(int) * NN);
  int*   rowptr = (int*)alloc(sizeof(int) * (NN + 1));
  int*   wp     = (int*)alloc(sizeof(int) * NN);
  int*   root   = (int*)alloc(sizeof(int) * GG);
  int*   eidx   = (int*)alloc(sizeof(int) * EE);
  float* agg    = (float*)alloc(sizeof(float) * NN * HH);
  float* hA     = (float*)alloc(sizeof(float) * NN * HH);
  float* hB     = (float*)alloc(sizeof(float) * NN * HH);
  float* hg     = (float*)alloc(sizeof(float) * GG * HH);
  float* news   = (float*)alloc(sizeof(float) * GG * HH);
  (void)ws_size; (void)n_in; (void)in_sizes; (void)out_size;

  hipMemsetAsync(deg, 0, sizeof(int) * NN, stream);
  hipMemsetAsync(root, 0x7F, sizeof(int) * GG, stream);

  hist_k<<<(EE + 255) / 256, 256, 0, stream>>>(dstp, deg);
  scan_k<<<1, 1024, 0, stream>>>(deg, rowptr, wp);
  scatter_k<<<(EE + 255) / 256, 256, 0, stream>>>(srcp, dstp, wp, eidx);
  root_k<<<(NN + 255) / 256, 256, 0, stream>>>(batch, root);

  const int AGG_GRID = NN / 4;              // 12500
  const int GEMM_GRID = (NN + 63) / 64;     // 782

  // layer 1
  agg_k<<<AGG_GRID, 256, 0, stream>>>(x, rowptr, eidx, agg);
  sage_k<<<GEMM_GRID, 256, 0, stream>>>(agg, x, W1l, b1l, W1r, hA);
  // layer 2
  agg_k<<<AGG_GRID, 256, 0, stream>>>(hA, rowptr, eidx, agg);
  sage_k<<<GEMM_GRID, 256, 0, stream>>>(agg, hA, W2l, b2l, W2r, hB);
  // layer 3
  agg_k<<<AGG_GRID, 256, 0, stream>>>(hB, rowptr, eidx, agg);
  sage_k<<<GEMM_GRID, 256, 0, stream>>>(agg, hB, W3l, b3l, W3r, hA);

  pool_k<<<GG, 128, 0, stream>>>(hA, root, hg);
  news_k<<<GG, 128, 0, stream>>>(x, root, Wnews, bnews, news);
  final_k<<<GG, 128, 0, stream>>>(hg, news, Wlin2, blin2, Wlin3, blin3, out);
}

// Round 2
// 352.908 us; speedup vs baseline: 1.7901x; 1.7901x over previous
//
#include <hip/hip_runtime.h>
#include <math.h>

#define NN 50000
#define EE 600000
#define GG 250
#define HH 128

typedef __attribute__((ext_vector_type(8))) short s16x8;
typedef __attribute__((ext_vector_type(8))) unsigned short u16x8;
typedef __attribute__((ext_vector_type(4))) unsigned short u16x4;
typedef __attribute__((ext_vector_type(4))) float f32x4;

__device__ __forceinline__ float b2f(unsigned short u) {
  union { unsigned int i; float f; } v; v.i = ((unsigned int)u) << 16; return v.f;
}
__device__ __forceinline__ unsigned short f2b(float f) {
  union { float f; unsigned int i; } v; v.f = f;
  unsigned int x = v.i;
  unsigned int r = (x + 0x7FFFu + ((x >> 16) & 1u)) >> 16;   // RNE, finite inputs
  return (unsigned short)r;
}

// ---------- dtype conversions ----------
__global__ void cvt_x_k(const float* __restrict__ x, unsigned short* __restrict__ xb) {
  int i = blockIdx.x * 256 + threadIdx.x;          // ×4 floats
  float4 v = *(const float4*)&x[i * 4];
  u16x4 o; o[0] = f2b(v.x); o[1] = f2b(v.y); o[2] = f2b(v.z); o[3] = f2b(v.w);
  *(u16x4*)&xb[i * 4] = o;
}

__global__ void cvtW_k(const float* __restrict__ W0, const float* __restrict__ W1,
                       const float* __restrict__ W2, const float* __restrict__ W3,
                       const float* __restrict__ W4, const float* __restrict__ W5,
                       unsigned short* __restrict__ WT) {
  int w = blockIdx.x >> 6;
  const float* W = (w == 0) ? W0 : (w == 1) ? W1 : (w == 2) ? W2
                   : (w == 3) ? W3 : (w == 4) ? W4 : W5;
  int idx = (blockIdx.x & 63) * 256 + threadIdx.x;  // 0..16383
  int j = idx >> 7, k = idx & 127;
  WT[w * 16384 + j * 128 + k] = f2b(W[k * 128 + j]);   // WT[col][k]
}

// ---------- CSR build ----------
__global__ void hist_k(const int* __restrict__ dst, int* __restrict__ deg) {
  int e = blockIdx.x * 256 + threadIdx.x;
  if (e < EE) atomicAdd(&deg[dst[e]], 1);
}

__global__ __launch_bounds__(1024) void scan1_k(const int* __restrict__ deg,
                                                int* __restrict__ excl,
                                                int* __restrict__ bsum) {
  __shared__ int sums[16];
  int tid = threadIdx.x;
  int i = blockIdx.x * 1024 + tid;
  int v = (i < NN) ? deg[i] : 0;
  int lane = tid & 63, wid = tid >> 6;
  int x = v;
  #pragma unroll
  for (int d = 1; d < 64; d <<= 1) { int y = __shfl_up(x, d); if (lane >= d) x += y; }
  if (lane == 63) sums[wid] = x;
  __syncthreads();
  if (wid == 0) {
    int s = (lane < 16) ? sums[lane] : 0;
    #pragma unroll
    for (int d = 1; d < 16; d <<= 1) { int y = __shfl_up(s, d); if (lane >= d) s += y; }
    if (lane < 16) sums[lane] = s;
  }
  __syncthreads();
  int ex = (wid ? sums[wid - 1] : 0) + x - v;
  if (i < NN) excl[i] = ex;
  if (tid == 1023) bsum[blockIdx.x] = sums[15];
}

__global__ void scan2_k(const int* __restrict__ bsum, int* __restrict__ boff) {
  int lane = threadIdx.x;              // 64 threads, NB=49
  int v = (lane < 49) ? bsum[lane] : 0;
  int x = v;
  #pragma unroll
  for (int d = 1; d < 64; d <<= 1) { int y = __shfl_up(x, d); if (lane >= d) x += y; }
  boff[lane] = x - v;
}

__global__ void scan3_k(const int* __restrict__ excl, const int* __restrict__ boff,
                        int* __restrict__ rowptr, int* __restrict__ wp) {
  int i = blockIdx.x * 256 + threadIdx.x;
  if (i < NN) {
    int r = excl[i] + boff[i >> 10];
    rowptr[i] = r; wp[i] = r;
  }
  if (i == 0) rowptr[NN] = EE;
}

__global__ void scatter_k(const int* __restrict__ src, const int* __restrict__ dst,
                          int* __restrict__ wp, int* __restrict__ eidx) {
  int e = blockIdx.x * 256 + threadIdx.x;
  if (e < EE) {
    int p = atomicAdd(&wp[dst[e]], 1);
    eidx[p] = src[e];
  }
}

__global__ void root_k(const int* __restrict__ batch, int* __restrict__ root) {
  int n = blockIdx.x * 256 + threadIdx.x;
  if (n < NN) atomicMin(&root[batch[n]], n);
}

// ---------- mean aggregation: 16 lanes per node, bf16 in/out ----------
__global__ __launch_bounds__(256) void agg_k(const unsigned short* __restrict__ hb,
                                             const int* __restrict__ rowptr,
                                             const int* __restrict__ eidx,
                                             unsigned short* __restrict__ aggb) {
  int lane = threadIdx.x & 63, wid = threadIdx.x >> 6;
  int sub = lane >> 4, l16 = lane & 15;
  int node = blockIdx.x * 16 + wid * 4 + sub;
  int start = rowptr[node], end = rowptr[node + 1];
  float acc[8] = {0.f, 0.f, 0.f, 0.f, 0.f, 0.f, 0.f, 0.f};
  int e = start;
  for (; e + 1 < end; e += 2) {
    int s0 = eidx[e], s1 = eidx[e + 1];
    u16x8 v0 = *(const u16x8*)&hb[s0 * HH + l16 * 8];
    u16x8 v1 = *(const u16x8*)&hb[s1 * HH + l16 * 8];
    #pragma unroll
    for (int j = 0; j < 8; ++j) acc[j] += b2f(v0[j]) + b2f(v1[j]);
  }
  if (e < end) {
    int s0 = eidx[e];
    u16x8 v0 = *(const u16x8*)&hb[s0 * HH + l16 * 8];
    #pragma unroll
    for (int j = 0; j < 8; ++j) acc[j] += b2f(v0[j]);
  }
  int c = end - start;
  float inv = 1.f / (float)(c > 0 ? c : 1);
  u16x8 o;
  #pragma unroll
  for (int j = 0; j < 8; ++j) o[j] = f2b(acc[j] * inv);
  *(u16x8*)&aggb[node * HH + l16 * 8] = o;
}

// ---------- fused MFMA: (agg@Wl + bl + h@Wr) -> L2norm -> relu -> bf16 ----------
__global__ __launch_bounds__(256) void sage_k(
    const unsigned short* __restrict__ aggb, const unsigned short* __restrict__ hb,
    const unsigned short* __restrict__ WlT, const float* __restrict__ bl,
    const unsigned short* __restrict__ WrT, unsigned short* __restrict__ hout) {
  int lane = threadIdx.x & 63, wid = threadIdx.x >> 6;
  int row0 = blockIdx.x * 64 + wid * 16;
  int l16 = lane & 15, hi = lane >> 4;
  int arow = row0 + l16; if (arow > NN - 1) arow = NN - 1;
  int aoff = arow * HH + hi * 8;
  int boff = l16 * HH + hi * 8;
  f32x4 acc[8];
  #pragma unroll
  for (int cc = 0; cc < 8; ++cc) acc[cc] = (f32x4){0.f, 0.f, 0.f, 0.f};
  #pragma unroll
  for (int kk = 0; kk < 4; ++kk) {
    s16x8 a = *(const s16x8*)&aggb[aoff + kk * 32];
    #pragma unroll
    for (int cc = 0; cc < 8; ++cc) {
      s16x8 b = *(const s16x8*)&WlT[boff + cc * 16 * HH + kk * 32];
      acc[cc] = __builtin_amdgcn_mfma_f32_16x16x32_bf16(a, b, acc[cc], 0, 0, 0);
    }
  }
  #pragma unroll
  for (int kk = 0; kk < 4; ++kk) {
    s16x8 a = *(const s16x8*)&hb[aoff + kk * 32];
    #pragma unroll
    for (int cc = 0; cc < 8; ++cc) {
      s16x8 b = *(const s16x8*)&WrT[boff + cc * 16 * HH + kk * 32];
      acc[cc] = __builtin_amdgcn_mfma_f32_16x16x32_bf16(a, b, acc[cc], 0, 0, 0);
    }
  }
  // bias, per-row L2 norm (rows owned by lanes sharing hi), relu, bf16 store
  float v[8][4];
  float ss[4] = {0.f, 0.f, 0.f, 0.f};
  #pragma unroll
  for (int cc = 0; cc < 8; ++cc) {
    float bb = bl[cc * 16 + l16];
    #pragma unroll
    for (int i = 0; i < 4; ++i) {
      float t = acc[cc][i] + bb;
      v[cc][i] = t;
      ss[i] += t * t;
    }
  }
  #pragma unroll
  for (int m = 1; m < 16; m <<= 1) {
    #pragma unroll
    for (int i = 0; i < 4; ++i) ss[i] += __shfl_xor(ss[i], m);
  }
  float inv[4];
  #pragma unroll
  for (int i = 0; i < 4; ++i) inv[i] = 1.f / fmaxf(sqrtf(ss[i]), 1e-12f);
  #pragma unroll
  for (int cc = 0; cc < 8; ++cc) {
    #pragma unroll
    for (int i = 0; i < 4; ++i) {
      int row = row0 + hi * 4 + i;
      if (row < NN)
        hout[row * HH + cc * 16 + l16] = f2b(fmaxf(v[cc][i] * inv[i], 0.f));
    }
  }
}

// ---------- global max pool per graph (bf16 in, f32 out) ----------
__global__ __launch_bounds__(512) void pool_k(const unsigned short* __restrict__ h,
                                              const int* __restrict__ root,
                                              float* __restrict__ hg) {
  __shared__ float red[512];
  int g = blockIdx.x;
  int col = threadIdx.x & 127, seg = threadIdx.x >> 7;
  int start = root[g], end = (g == GG - 1) ? NN : root[g + 1];
  float m = -1e30f;
  for (int r = start + seg; r < end; r += 4) m = fmaxf(m, b2f(h[r * HH + col]));
  red[threadIdx.x] = m;
  __syncthreads();
  if (seg == 0) {
    m = fmaxf(fmaxf(red[col], red[col + 128]), fmaxf(red[col + 256], red[col + 384]));
    hg[g * HH + col] = m;
  }
}

// ---------- news = relu(x[root] @ Wnews + b) ----------
__global__ void news_k(const float* __restrict__ x, const int* __restrict__ root,
                       const float* __restrict__ W, const float* __restrict__ b,
                       float* __restrict__ news) {
  __shared__ float xr[128];
  int g = blockIdx.x, j = threadIdx.x;
  int r = root[g];
  xr[j] = x[r * HH + j];
  __syncthreads();
  float acc = b[j];
  for (int k = 0; k < 128; ++k) acc += xr[k] * W[k * HH + j];
  news[g * HH + j] = fmaxf(acc, 0.f);
}

// ---------- hg2 = relu(hg@Wlin2+b2); out = sigmoid([hg2,news]@Wlin3+b3) ----------
__global__ void final_k(const float* __restrict__ hg, const float* __restrict__ news,
                        const float* __restrict__ W2, const float* __restrict__ b2,
                        const float* __restrict__ W3, const float* __restrict__ b3,
                        float* __restrict__ out) {
  __shared__ float hgr[128];
  __shared__ float red[2];
  int g = blockIdx.x, j = threadIdx.x;
  hgr[j] = hg[g * HH + j];
  __syncthreads();
  float acc = b2[j];
  for (int k = 0; k < 128; ++k) acc += hgr[k] * W2[k * HH + j];
  float v2 = fmaxf(acc, 0.f);
  float c = v2 * W3[j] + news[g * HH + j] * W3[HH + j];
  #pragma unroll
  for (int d = 1; d < 64; d <<= 1) c += __shfl_xor(c, d);
  if ((j & 63) == 0) red[j >> 6] = c;
  __syncthreads();
  if (j == 0) {
    float z = red[0] + red[1] + b3[0];
    out[g] = 1.f / (1.f + expf(-z));
  }
}

extern "C" void kernel_launch(void* const* d_in, const int* in_sizes, int n_in,
                              void* d_out, int out_size, void* d_ws, size_t ws_size,
                              hipStream_t stream) {
  const float* x     = (const float*)d_in[0];
  const int*   adj   = (const int*)d_in[1];
  const int*   batch = (const int*)d_in[2];
  const float *W1l = (const float*)d_in[3],  *b1l = (const float*)d_in[4],  *W1r = (const float*)d_in[5];
  const float *W2l = (const float*)d_in[6],  *b2l = (const float*)d_in[7],  *W2r = (const float*)d_in[8];
  const float *W3l = (const float*)d_in[9],  *b3l = (const float*)d_in[10], *W3r = (const float*)d_in[11];
  const float *Wnews = (const float*)d_in[12], *bnews = (const float*)d_in[13];
  const float *Wlin2 = (const float*)d_in[14], *blin2 = (const float*)d_in[15];
  const float *Wlin3 = (const float*)d_in[16], *blin3 = (const float*)d_in[17];
  float* out = (float*)d_out;

  const int* srcp = adj;
  const int* dstp = adj + EE;

  char* ws = (char*)d_ws;
  size_t off = 0;
  auto alloc = [&](size_t bytes) -> void* {
    void* p = ws + off;
    off = (off + bytes + 255) & ~(size_t)255;
    return p;
  };
  int*   deg    = (int*)alloc(sizeof(int) * NN);
  int*   excl   = (int*)alloc(sizeof(int) * NN);
  int*   bsum   = (int*)alloc(sizeof(int) * 64);
  int*   boffp  = (int*)alloc(sizeof(int) * 64);
  int*   rowptr = (int*)alloc(sizeof(int) * (NN + 1));
  int*   wp     = (int*)alloc(sizeof(int) * NN);
  int*   root   = (int*)alloc(sizeof(int) * GG);
  int*   eidx   = (int*)alloc(sizeof(int) * EE);
  unsigned short* WT   = (unsigned short*)alloc(sizeof(short) * 6 * 128 * 128);
  unsigned short* xb   = (unsigned short*)alloc(sizeof(short) * NN * HH);
  unsigned short* aggb = (unsigned short*)alloc(sizeof(short) * NN * HH);
  unsigned short* h1   = (unsigned short*)alloc(sizeof(short) * NN * HH);
  unsigned short* h2   = (unsigned short*)alloc(sizeof(short) * NN * HH);
  float* hg   = (float*)alloc(sizeof(float) * GG * HH);
  float* news = (float*)alloc(sizeof(float) * GG * HH);
  (void)ws_size; (void)n_in; (void)in_sizes; (void)out_size;

  hipMemsetAsync(deg, 0, sizeof(int) * NN, stream);
  hipMemsetAsync(root, 0x7F, sizeof(int) * GG, stream);

  // conversions (independent of CSR)
  cvt_x_k<<<NN * HH / 1024, 256, 0, stream>>>(x, xb);
  cvtW_k<<<384, 256, 0, stream>>>(W1l, W1r, W2l, W2r, W3l, W3r, WT);

  // CSR
  hist_k<<<(EE + 255) / 256, 256, 0, stream>>>(dstp, deg);
  scan1_k<<<(NN + 1023) / 1024, 1024, 0, stream>>>(deg, excl, bsum);
  scan2_k<<<1, 64, 0, stream>>>(bsum, boffp);
  scan3_k<<<(NN + 255) / 256, 256, 0, stream>>>(excl, boffp, rowptr, wp);
  scatter_k<<<(EE + 255) / 256, 256, 0, stream>>>(srcp, dstp, wp, eidx);
  root_k<<<(NN + 255) / 256, 256, 0, stream>>>(batch, root);

  const int AGG_GRID = NN / 16;             // 3125
  const int GEMM_GRID = (NN + 63) / 64;     // 782
  const unsigned short* W1lT = WT + 0 * 16384;
  const unsigned short* W1rT = WT + 1 * 16384;
  const unsigned short* W2lT = WT + 2 * 16384;
  const unsigned short* W2rT = WT + 3 * 16384;
  const unsigned short* W3lT = WT + 4 * 16384;
  const unsigned short* W3rT = WT + 5 * 16384;

  agg_k<<<AGG_GRID, 256, 0, stream>>>(xb, rowptr, eidx, aggb);
  sage_k<<<GEMM_GRID, 256, 0, stream>>>(aggb, xb, W1lT, b1l, W1rT, h1);
  agg_k<<<AGG_GRID, 256, 0, stream>>>(h1, rowptr, eidx, aggb);
  sage_k<<<GEMM_GRID, 256, 0, stream>>>(aggb, h1, W2lT, b2l, W2rT, h2);
  agg_k<<<AGG_GRID, 256, 0, stream>>>(h2, rowptr, eidx, aggb);
  sage_k<<<GEMM_GRID, 256, 0, stream>>>(aggb, h2, W3lT, b3l, W3rT, h1);

  pool_k<<<GG, 512, 0, stream>>>(h1, root, hg);
  news_k<<<GG, 128, 0, stream>>>(x, root, Wnews, bnews, news);
  final_k<<<GG, 128, 0, stream>>>(hg, news, Wlin2, blin2, Wlin3, blin3, out);
}

// Round 3
// 284.765 us; speedup vs baseline: 2.2185x; 1.2393x over previous
//
#include <hip/hip_runtime.h>
#include <math.h>

#define NN 50000
#define EE 600000
#define GG 250
#define HH 128

typedef __attribute__((ext_vector_type(8))) short s16x8;
typedef __attribute__((ext_vector_type(8))) unsigned short u16x8;
typedef __attribute__((ext_vector_type(4))) unsigned short u16x4;
typedef __attribute__((ext_vector_type(4))) float f32x4;

__device__ __forceinline__ float b2f(unsigned short u) {
  union { unsigned int i; float f; } v; v.i = ((unsigned int)u) << 16; return v.f;
}
__device__ __forceinline__ unsigned short f2b(float f) {
  union { float f; unsigned int i; } v; v.f = f;
  unsigned int x = v.i;
  unsigned int r = (x + 0x7FFFu + ((x >> 16) & 1u)) >> 16;   // RNE, finite inputs
  return (unsigned short)r;
}

// ---------- dtype conversions ----------
__global__ void cvt_x_k(const float* __restrict__ x, unsigned short* __restrict__ xb) {
  int i = blockIdx.x * 256 + threadIdx.x;          // ×4 floats
  float4 v = *(const float4*)&x[i * 4];
  u16x4 o; o[0] = f2b(v.x); o[1] = f2b(v.y); o[2] = f2b(v.z); o[3] = f2b(v.w);
  *(u16x4*)&xb[i * 4] = o;
}

__global__ void cvtW_k(const float* __restrict__ W0, const float* __restrict__ W1,
                       const float* __restrict__ W2, const float* __restrict__ W3,
                       const float* __restrict__ W4, const float* __restrict__ W5,
                       unsigned short* __restrict__ WT) {
  int w = blockIdx.x >> 6;
  const float* W = (w == 0) ? W0 : (w == 1) ? W1 : (w == 2) ? W2
                   : (w == 3) ? W3 : (w == 4) ? W4 : W5;
  int idx = (blockIdx.x & 63) * 256 + threadIdx.x;  // 0..16383
  int j = idx >> 7, k = idx & 127;
  WT[w * 16384 + j * 128 + k] = f2b(W[k * 128 + j]);   // WT[col][k]
}

// ---------- CSR build ----------
__global__ void hist_k(const int* __restrict__ dst, int* __restrict__ deg) {
  int e = blockIdx.x * 256 + threadIdx.x;
  if (e < EE) atomicAdd(&deg[dst[e]], 1);
}

__global__ __launch_bounds__(1024) void scan1_k(const int* __restrict__ deg,
                                                int* __restrict__ excl,
                                                int* __restrict__ bsum) {
  __shared__ int sums[16];
  int tid = threadIdx.x;
  int i = blockIdx.x * 1024 + tid;
  int v = (i < NN) ? deg[i] : 0;
  int lane = tid & 63, wid = tid >> 6;
  int x = v;
  #pragma unroll
  for (int d = 1; d < 64; d <<= 1) { int y = __shfl_up(x, d); if (lane >= d) x += y; }
  if (lane == 63) sums[wid] = x;
  __syncthreads();
  if (wid == 0) {
    int s = (lane < 16) ? sums[lane] : 0;
    #pragma unroll
    for (int d = 1; d < 16; d <<= 1) { int y = __shfl_up(s, d); if (lane >= d) s += y; }
    if (lane < 16) sums[lane] = s;
  }
  __syncthreads();
  int ex = (wid ? sums[wid - 1] : 0) + x - v;
  if (i < NN) excl[i] = ex;
  if (tid == 1023) bsum[blockIdx.x] = sums[15];
}

__global__ void scan2_k(const int* __restrict__ bsum, int* __restrict__ boff) {
  int lane = threadIdx.x;              // 64 threads, NB=49
  int v = (lane < 49) ? bsum[lane] : 0;
  int x = v;
  #pragma unroll
  for (int d = 1; d < 64; d <<= 1) { int y = __shfl_up(x, d); if (lane >= d) x += y; }
  boff[lane] = x - v;
}

__global__ void scan3_k(const int* __restrict__ excl, const int* __restrict__ boff,
                        int* __restrict__ rowptr, int* __restrict__ wp) {
  int i = blockIdx.x * 256 + threadIdx.x;
  if (i < NN) {
    int r = excl[i] + boff[i >> 10];
    rowptr[i] = r; wp[i] = r;
  }
  if (i == 0) rowptr[NN] = EE;
}

__global__ void scatter_k(const int* __restrict__ src, const int* __restrict__ dst,
                          int* __restrict__ wp, int* __restrict__ eidx) {
  int e = blockIdx.x * 256 + threadIdx.x;
  if (e < EE) {
    int p = atomicAdd(&wp[dst[e]], 1);
    eidx[p] = src[e];
  }
}

// batch is sorted -> segment_min == boundary detection, no atomics
__global__ void root_k(const int* __restrict__ batch, int* __restrict__ root) {
  int n = blockIdx.x * 256 + threadIdx.x;
  if (n < NN) {
    int b = batch[n];
    if (n == 0 || batch[n - 1] != b) root[b] = n;
  }
}

// ---------- mean aggregation: 16 lanes per node, bf16 in/out ----------
__global__ __launch_bounds__(256) void agg_k(const unsigned short* __restrict__ hb,
                                             const int* __restrict__ rowptr,
                                             const int* __restrict__ eidx,
                                             unsigned short* __restrict__ aggb) {
  int lane = threadIdx.x & 63, wid = threadIdx.x >> 6;
  int sub = lane >> 4, l16 = lane & 15;
  int node = blockIdx.x * 16 + wid * 4 + sub;
  int start = rowptr[node], end = rowptr[node + 1];
  float acc[8] = {0.f, 0.f, 0.f, 0.f, 0.f, 0.f, 0.f, 0.f};
  int e = start;
  for (; e + 3 < end; e += 4) {
    int s0 = eidx[e], s1 = eidx[e + 1], s2 = eidx[e + 2], s3 = eidx[e + 3];
    u16x8 v0 = *(const u16x8*)&hb[s0 * HH + l16 * 8];
    u16x8 v1 = *(const u16x8*)&hb[s1 * HH + l16 * 8];
    u16x8 v2 = *(const u16x8*)&hb[s2 * HH + l16 * 8];
    u16x8 v3 = *(const u16x8*)&hb[s3 * HH + l16 * 8];
    #pragma unroll
    for (int j = 0; j < 8; ++j)
      acc[j] += (b2f(v0[j]) + b2f(v1[j])) + (b2f(v2[j]) + b2f(v3[j]));
  }
  for (; e < end; ++e) {
    int s0 = eidx[e];
    u16x8 v0 = *(const u16x8*)&hb[s0 * HH + l16 * 8];
    #pragma unroll
    for (int j = 0; j < 8; ++j) acc[j] += b2f(v0[j]);
  }
  int c = end - start;
  float inv = 1.f / (float)(c > 0 ? c : 1);
  u16x8 o;
  #pragma unroll
  for (int j = 0; j < 8; ++j) o[j] = f2b(acc[j] * inv);
  *(u16x8*)&aggb[node * HH + l16 * 8] = o;
}

// ---------- fused MFMA: (agg@Wl + bl + h@Wr) -> L2norm -> relu -> bf16 ----------
__global__ __launch_bounds__(256) void sage_k(
    const unsigned short* __restrict__ aggb, const unsigned short* __restrict__ hb,
    const unsigned short* __restrict__ WlT, const float* __restrict__ bl,
    const unsigned short* __restrict__ WrT, unsigned short* __restrict__ hout) {
  int lane = threadIdx.x & 63, wid = threadIdx.x >> 6;
  int row0 = blockIdx.x * 64 + wid * 16;
  int l16 = lane & 15, hi = lane >> 4;
  int arow = row0 + l16; if (arow > NN - 1) arow = NN - 1;
  int aoff = arow * HH + hi * 8;
  int boff = l16 * HH + hi * 8;
  f32x4 acc[8];
  #pragma unroll
  for (int cc = 0; cc < 8; ++cc) acc[cc] = (f32x4){0.f, 0.f, 0.f, 0.f};
  #pragma unroll
  for (int kk = 0; kk < 4; ++kk) {
    s16x8 a = *(const s16x8*)&aggb[aoff + kk * 32];
    #pragma unroll
    for (int cc = 0; cc < 8; ++cc) {
      s16x8 b = *(const s16x8*)&WlT[boff + cc * 16 * HH + kk * 32];
      acc[cc] = __builtin_amdgcn_mfma_f32_16x16x32_bf16(a, b, acc[cc], 0, 0, 0);
    }
  }
  #pragma unroll
  for (int kk = 0; kk < 4; ++kk) {
    s16x8 a = *(const s16x8*)&hb[aoff + kk * 32];
    #pragma unroll
    for (int cc = 0; cc < 8; ++cc) {
      s16x8 b = *(const s16x8*)&WrT[boff + cc * 16 * HH + kk * 32];
      acc[cc] = __builtin_amdgcn_mfma_f32_16x16x32_bf16(a, b, acc[cc], 0, 0, 0);
    }
  }
  // bias, per-row L2 norm (rows owned by lanes sharing hi), relu, bf16 store
  float v[8][4];
  float ss[4] = {0.f, 0.f, 0.f, 0.f};
  #pragma unroll
  for (int cc = 0; cc < 8; ++cc) {
    float bb = bl[cc * 16 + l16];
    #pragma unroll
    for (int i = 0; i < 4; ++i) {
      float t = acc[cc][i] + bb;
      v[cc][i] = t;
      ss[i] += t * t;
    }
  }
  #pragma unroll
  for (int m = 1; m < 16; m <<= 1) {
    #pragma unroll
    for (int i = 0; i < 4; ++i) ss[i] += __shfl_xor(ss[i], m);
  }
  float inv[4];
  #pragma unroll
  for (int i = 0; i < 4; ++i) inv[i] = 1.f / fmaxf(sqrtf(ss[i]), 1e-12f);
  #pragma unroll
  for (int cc = 0; cc < 8; ++cc) {
    #pragma unroll
    for (int i = 0; i < 4; ++i) {
      int row = row0 + hi * 4 + i;
      if (row < NN)
        hout[row * HH + cc * 16 + l16] = f2b(fmaxf(v[cc][i] * inv[i], 0.f));
    }
  }
}

// ---------- global max pool per graph (bf16 in, f32 out) ----------
__global__ __launch_bounds__(512) void pool_k(const unsigned short* __restrict__ h,
                                              const int* __restrict__ root,
                                              float* __restrict__ hg) {
  __shared__ float red[512];
  int g = blockIdx.x;
  int col = threadIdx.x & 127, seg = threadIdx.x >> 7;
  int start = root[g], end = (g == GG - 1) ? NN : root[g + 1];
  float m = -1e30f;
  for (int r = start + seg; r < end; r += 4) m = fmaxf(m, b2f(h[r * HH + col]));
  red[threadIdx.x] = m;
  __syncthreads();
  if (seg == 0) {
    m = fmaxf(fmaxf(red[col], red[col + 128]), fmaxf(red[col + 256], red[col + 384]));
    hg[g * HH + col] = m;
  }
}

// ---------- fused: news + lin2 + lin3 + sigmoid ----------
__global__ void final_k(const float* __restrict__ hg, const float* __restrict__ x,
                        const int* __restrict__ root,
                        const float* __restrict__ Wn, const float* __restrict__ bn,
                        const float* __restrict__ W2, const float* __restrict__ b2,
                        const float* __restrict__ W3, const float* __restrict__ b3,
                        float* __restrict__ out) {
  __shared__ float hgr[128];
  __shared__ float xr[128];
  __shared__ float red[2];
  int g = blockIdx.x, j = threadIdx.x;
  int r = root[g];
  hgr[j] = hg[g * HH + j];
  xr[j] = x[r * HH + j];
  __syncthreads();
  float acc2 = b2[j];
  float accn = bn[j];
  for (int k = 0; k < 128; ++k) {
    acc2 += hgr[k] * W2[k * HH + j];
    accn += xr[k] * Wn[k * HH + j];
  }
  float v2 = fmaxf(acc2, 0.f);
  float vn = fmaxf(accn, 0.f);
  float c = v2 * W3[j] + vn * W3[HH + j];
  #pragma unroll
  for (int d = 1; d < 64; d <<= 1) c += __shfl_xor(c, d);
  if ((j & 63) == 0) red[j >> 6] = c;
  __syncthreads();
  if (j == 0) {
    float z = red[0] + red[1] + b3[0];
    out[g] = 1.f / (1.f + expf(-z));
  }
}

extern "C" void kernel_launch(void* const* d_in, const int* in_sizes, int n_in,
                              void* d_out, int out_size, void* d_ws, size_t ws_size,
                              hipStream_t stream) {
  const float* x     = (const float*)d_in[0];
  const int*   adj   = (const int*)d_in[1];
  const int*   batch = (const int*)d_in[2];
  const float *W1l = (const float*)d_in[3],  *b1l = (const float*)d_in[4],  *W1r = (const float*)d_in[5];
  const float *W2l = (const float*)d_in[6],  *b2l = (const float*)d_in[7],  *W2r = (const float*)d_in[8];
  const float *W3l = (const float*)d_in[9],  *b3l = (const float*)d_in[10], *W3r = (const float*)d_in[11];
  const float *Wnews = (const float*)d_in[12], *bnews = (const float*)d_in[13];
  const float *Wlin2 = (const float*)d_in[14], *blin2 = (const float*)d_in[15];
  const float *Wlin3 = (const float*)d_in[16], *blin3 = (const float*)d_in[17];
  float* out = (float*)d_out;

  const int* srcp = adj;
  const int* dstp = adj + EE;

  char* ws = (char*)d_ws;
  size_t off = 0;
  auto alloc = [&](size_t bytes) -> void* {
    void* p = ws + off;
    off = (off + bytes + 255) & ~(size_t)255;
    return p;
  };
  int*   deg    = (int*)alloc(sizeof(int) * NN);
  int*   excl   = (int*)alloc(sizeof(int) * NN);
  int*   bsum   = (int*)alloc(sizeof(int) * 64);
  int*   boffp  = (int*)alloc(sizeof(int) * 64);
  int*   rowptr = (int*)alloc(sizeof(int) * (NN + 1));
  int*   wp     = (int*)alloc(sizeof(int) * NN);
  int*   root   = (int*)alloc(sizeof(int) * GG);
  int*   eidx   = (int*)alloc(sizeof(int) * EE);
  unsigned short* WT   = (unsigned short*)alloc(sizeof(short) * 6 * 128 * 128);
  unsigned short* xb   = (unsigned short*)alloc(sizeof(short) * NN * HH);
  unsigned short* aggb = (unsigned short*)alloc(sizeof(short) * NN * HH);
  unsigned short* h1   = (unsigned short*)alloc(sizeof(short) * NN * HH);
  unsigned short* h2   = (unsigned short*)alloc(sizeof(short) * NN * HH);
  float* hg   = (float*)alloc(sizeof(float) * GG * HH);
  (void)ws_size; (void)n_in; (void)in_sizes; (void)out_size;

  hipMemsetAsync(deg, 0, sizeof(int) * NN, stream);
  hipMemsetAsync(root, 0x7F, sizeof(int) * GG, stream);

  // conversions (independent of CSR)
  cvt_x_k<<<NN * HH / 1024, 256, 0, stream>>>(x, xb);
  cvtW_k<<<384, 256, 0, stream>>>(W1l, W1r, W2l, W2r, W3l, W3r, WT);

  // CSR
  hist_k<<<(EE + 255) / 256, 256, 0, stream>>>(dstp, deg);
  scan1_k<<<(NN + 1023) / 1024, 1024, 0, stream>>>(deg, excl, bsum);
  scan2_k<<<1, 64, 0, stream>>>(bsum, boffp);
  scan3_k<<<(NN + 255) / 256, 256, 0, stream>>>(excl, boffp, rowptr, wp);
  scatter_k<<<(EE + 255) / 256, 256, 0, stream>>>(srcp, dstp, wp, eidx);
  root_k<<<(NN + 255) / 256, 256, 0, stream>>>(batch, root);

  const int AGG_GRID = NN / 16;             // 3125
  const int GEMM_GRID = (NN + 63) / 64;     // 782
  const unsigned short* W1lT = WT + 0 * 16384;
  const unsigned short* W1rT = WT + 1 * 16384;
  const unsigned short* W2lT = WT + 2 * 16384;
  const unsigned short* W2rT = WT + 3 * 16384;
  const unsigned short* W3lT = WT + 4 * 16384;
  const unsigned short* W3rT = WT + 5 * 16384;

  agg_k<<<AGG_GRID, 256, 0, stream>>>(xb, rowptr, eidx, aggb);
  sage_k<<<GEMM_GRID, 256, 0, stream>>>(aggb, xb, W1lT, b1l, W1rT, h1);
  agg_k<<<AGG_GRID, 256, 0, stream>>>(h1, rowptr, eidx, aggb);
  sage_k<<<GEMM_GRID, 256, 0, stream>>>(aggb, h1, W2lT, b2l, W2rT, h2);
  agg_k<<<AGG_GRID, 256, 0, stream>>>(h2, rowptr, eidx, aggb);
  sage_k<<<GEMM_GRID, 256, 0, stream>>>(aggb, h2, W3lT, b3l, W3rT, h1);

  pool_k<<<GG, 512, 0, stream>>>(h1, root, hg);
  final_k<<<GG, 128, 0, stream>>>(hg, x, root, Wnews, bnews,
                                  Wlin2, blin2, Wlin3, blin3, out);
}